// Round 1
// baseline (613.083 us; speedup 1.0000x reference)
//
#include <hip/hip_runtime.h>
#include <hip/hip_bf16.h>

// Model dims
#define NN 2048
#define DS 64
#define DI 256
#define DV 64
#define KK 512
#define HH 4
#define HD 16
#define MULT 4
#define BB 2
#define TT 4
#define DCAT 192      // DS + DS + DV
#define G2 512        // 2*MULT*DS
#define GU 256        // MULT*DS

__device__ __forceinline__ float wave_sum(float v) {
#pragma unroll
    for (int o = 32; o > 0; o >>= 1) v += __shfl_xor(v, o);
    return v;
}
__device__ __forceinline__ float wave_max(float v) {
#pragma unroll
    for (int o = 32; o > 0; o >>= 1) v = fmaxf(v, __shfl_xor(v, o));
    return v;
}

// ---------------------------------------------------------------- K1: gate + x_proj
__global__ __launch_bounds__(256) void k_gate_xproj(
    const float* __restrict__ h, const float* __restrict__ W_gate,
    const float* __restrict__ x, const float* __restrict__ W_in,
    float* __restrict__ gate, float* __restrict__ xproj, int t)
{
    int tid = blockIdx.x * blockDim.x + threadIdx.x;
    if (tid < BB * NN) {
        const float* hp = h + tid * DS;
        float acc = 0.f;
#pragma unroll
        for (int d = 0; d < DS; d++) acc += hp[d] * W_gate[d];
        gate[tid] = acc;
    } else {
        int u = tid - BB * NN;
        if (u < BB * DS) {
            int b = u / DS, dsi = u % DS;
            const float* xp = x + (b * TT + t) * DI;
            const float* wr = W_in + dsi * DI;
            float acc = 0.f;
#pragma unroll 4
            for (int i = 0; i < DI; i++) acc += xp[i] * wr[i];
            xproj[u] = acc;
        }
    }
}

// ---------------------------------------------------------------- K2: top-k via bitonic sort
// key = (orderable(gate) << 32) | (N-1-i): ascending sort; top-K at the end;
// ties resolved to the SMALLEST column index (matches jax.lax.top_k).
__global__ __launch_bounds__(1024) void k_topk(
    const float* __restrict__ gate, int* __restrict__ col2slot, int* __restrict__ act_idx)
{
    int b = blockIdx.x;
    __shared__ unsigned long long keys[NN];
    __shared__ int slots[NN];
    int tid = threadIdx.x;
    for (int i = tid; i < NN; i += 1024) {
        float g = gate[b * NN + i];
        unsigned u = __float_as_uint(g);
        u = (u & 0x80000000u) ? ~u : (u | 0x80000000u);
        keys[i] = ((unsigned long long)u << 32) | (unsigned)(NN - 1 - i);
        slots[i] = -1;
    }
    __syncthreads();
    for (int k = 2; k <= NN; k <<= 1) {
        for (int j = k >> 1; j > 0; j >>= 1) {
            for (int base = 0; base < NN; base += 1024) {
                int i = base + tid;
                int ixj = i ^ j;
                if (ixj > i) {
                    unsigned long long a = keys[i], c = keys[ixj];
                    bool up = ((i & k) == 0);
                    if ((a > c) == up) { keys[i] = c; keys[ixj] = a; }
                }
            }
            __syncthreads();
        }
    }
    if (tid < KK) {
        int pos = NN - 1 - tid;                       // tid-th largest
        int n = NN - 1 - (int)(keys[pos] & 0xFFFFFFFFu);
        act_idx[b * KK + tid] = n;
        slots[n] = tid;
    }
    __syncthreads();
    for (int i = tid; i < NN; i += 1024) col2slot[b * NN + i] = slots[i];
}

// ---------------------------------------------------------------- K3: column core (active only)
// one wave per active column; h updated in place (ms == 1 for active)
__global__ __launch_bounds__(256) void k_core(
    float* __restrict__ h, const float* __restrict__ xproj, const int* __restrict__ act_idx,
    const float* __restrict__ norm_w, const float* __restrict__ Wg, const float* __restrict__ Wout)
{
    __shared__ float zbuf[4][128];
    __shared__ float ubuf[4][GU];
    int wave = threadIdx.x >> 6, lane = threadIdx.x & 63;
    int task = blockIdx.x * 4 + wave;                 // 0 .. B*K-1
    int b = task / KK, slot = task % KK;
    int n = act_idx[b * KK + slot];
    float* hp = h + (b * NN + n) * DS;
    float hv = hp[lane];
    float xv = xproj[b * DS + lane];
    float ss = wave_sum(hv * hv + xv * xv);
    float rs = rsqrtf(ss * (1.0f / DCAT) + 1e-6f);    // m-part is zeros; counts in mean
    zbuf[wave][lane] = norm_w[lane] * hv * rs;
    zbuf[wave][64 + lane] = norm_w[64 + lane] * xv * rs;
    __syncthreads();
    float g[8];
#pragma unroll
    for (int jj = 0; jj < 8; jj++) {
        int o = jj * 64 + lane;
        const float* wr = Wg + o * DCAT;              // only first 128 cols matter (z_m == 0)
        float acc = 0.f;
#pragma unroll
        for (int d = 0; d < 128; d += 4) {
            acc += zbuf[wave][d] * wr[d] + zbuf[wave][d + 1] * wr[d + 1]
                 + zbuf[wave][d + 2] * wr[d + 2] + zbuf[wave][d + 3] * wr[d + 3];
        }
        g[jj] = acc;
    }
#pragma unroll
    for (int jj = 0; jj < 4; jj++) {
        float a = g[jj], bv = g[jj + 4];
        float s = bv / (1.0f + expf(-bv));            // silu
        ubuf[wave][jj * 64 + lane] = a * s;
    }
    __syncthreads();
    const float* wr = Wout + lane * GU;
    float acc = 0.f;
#pragma unroll 8
    for (int d = 0; d < GU; d++) acc += ubuf[wave][d] * wr[d];
    hp[lane] = hv + acc;                              // h = h_hat for active columns
}

// ---------------------------------------------------------------- K4: votes + qkv (active only)
__global__ __launch_bounds__(256) void k_votes(
    const float* __restrict__ h, const int* __restrict__ act_idx,
    const float* __restrict__ W_vote, const float* __restrict__ attn_in_w,
    float* __restrict__ qh, float* __restrict__ kh, float* __restrict__ vh)
{
    __shared__ float hbuf[4][64];
    __shared__ float vbuf[4][64];
    int wave = threadIdx.x >> 6, lane = threadIdx.x & 63;
    int task = blockIdx.x * 4 + wave;
    int b = task / KK, slot = task % KK;
    int n = act_idx[b * KK + slot];
    hbuf[wave][lane] = h[(b * NN + n) * DS + lane];
    __syncthreads();
    const float* wv = W_vote + lane * DS;
    float v = 0.f;
#pragma unroll
    for (int d = 0; d < DS; d++) v += hbuf[wave][d] * wv[d];
    vbuf[wave][lane] = v;
    __syncthreads();
    const float* wq = attn_in_w + lane * DV;
    const float* wk = attn_in_w + (DV + lane) * DV;
    const float* wvv = attn_in_w + (2 * DV + lane) * DV;
    float q = 0.f, k = 0.f, vv = 0.f;
#pragma unroll
    for (int d = 0; d < DV; d++) {
        float z = vbuf[wave][d];
        q += z * wq[d]; k += z * wk[d]; vv += z * wvv[d];
    }
    int head = lane >> 4, hd = lane & 15;
    int idx = ((b * HH + head) * KK + slot) * HD + hd;  // layout (B,H,K,HD)
    qh[idx] = q; kh[idx] = k; vh[idx] = vv;
}

// ---------------------------------------------------------------- K5: attention for ACTIVE queries
// one wave per (b, head, query-slot); 8 keys per lane
__global__ __launch_bounds__(256) void k_attn(
    const float* __restrict__ qh, const float* __restrict__ kh, const float* __restrict__ vh,
    float* __restrict__ m_raw)
{
    int wave = threadIdx.x >> 6, lane = threadIdx.x & 63;
    int task = blockIdx.x * 4 + wave;                 // (b*H+head)*K + qs
    int qs = task % KK;
    int bh = task / KK;
    const float* qp = qh + (bh * KK + qs) * HD;
    float q[HD];
#pragma unroll
    for (int d = 0; d < HD; d++) q[d] = qp[d];
    const float* kp = kh + bh * KK * HD;
    const float* vp = vh + bh * KK * HD;
    float lg[8];
    float mx = -1e30f;
#pragma unroll
    for (int i = 0; i < 8; i++) {
        const float* kr = kp + (i * 64 + lane) * HD;
        float acc = 0.f;
#pragma unroll
        for (int d = 0; d < HD; d++) acc += q[d] * kr[d];
        lg[i] = acc * 0.25f;                          // 1/sqrt(16)
        mx = fmaxf(mx, lg[i]);
    }
    mx = wave_max(mx);
    float p[8]; float sum = 0.f;
#pragma unroll
    for (int i = 0; i < 8; i++) { p[i] = expf(lg[i] - mx); sum += p[i]; }
    sum = wave_sum(sum);
    float inv = 1.0f / sum;
    float acc[HD];
#pragma unroll
    for (int d = 0; d < HD; d++) acc[d] = 0.f;
#pragma unroll
    for (int i = 0; i < 8; i++) {
        const float* vr = vp + (i * 64 + lane) * HD;
        float pi = p[i];
#pragma unroll
        for (int d = 0; d < HD; d++) acc[d] += pi * vr[d];
    }
#pragma unroll
    for (int d = 0; d < HD; d++) acc[d] = wave_sum(acc[d]) * inv;
    if (lane == 0) {
        int b = bh / HH, head = bh % HH;
        float* mp = m_raw + (b * KK + qs) * DV + head * HD;
#pragma unroll
        for (int d = 0; d < HD; d++) mp[d] = acc[d];
    }
}

// ---------------------------------------------------------------- K5c: mean message + FiLM vectors for inactive columns
__global__ __launch_bounds__(512) void k_meanfilm(
    const float* __restrict__ vh, const float* __restrict__ attn_out_w,
    const float* __restrict__ Wfs, const float* __restrict__ Wfsh,
    float* __restrict__ fsm, float* __restrict__ fshm)
{
    __shared__ float partial[512];
    __shared__ float mr[BB][64], mo[BB][64];
    int t = threadIdx.x;
    int bd = t & 127, sub = t >> 7;                   // 4 sub-summers per (b,d)
    int b = bd >> 6, d = bd & 63;
    int head = d >> 4, hd = d & 15;
    const float* vp = vh + ((b * HH + head) * KK) * HD + hd;
    float s = 0.f;
    for (int ks = sub * 128; ks < sub * 128 + 128; ks++) s += vp[ks * HD];
    partial[t] = s;
    __syncthreads();
    if (t < 128) {
        float tot = partial[t] + partial[t + 128] + partial[t + 256] + partial[t + 384];
        mr[b][d] = tot * (1.0f / KK);                 // uniform attention = mean of vh
    }
    __syncthreads();
    if (t < 128) {
        const float* wo = attn_out_w + d * DV;
        float acc = 0.f;
#pragma unroll
        for (int e = 0; e < DV; e++) acc += mr[b][e] * wo[e];
        mo[b][d] = acc;
    }
    __syncthreads();
    if (t < 128) {
        const float* ws = Wfs + d * DV;
        const float* wsh = Wfsh + d * DV;
        float sc = 0.f, sh = 0.f;
#pragma unroll
        for (int e = 0; e < DV; e++) { float z = mo[b][e]; sc += z * ws[e]; sh += z * wsh[e]; }
        fsm[b * DS + d] = tanhf(sc);
        fshm[b * DS + d] = sh;
    }
}

// ---------------------------------------------------------------- K6: FiLM for ALL columns
__global__ __launch_bounds__(256) void k_film(
    float* __restrict__ h, const int* __restrict__ col2slot, const float* __restrict__ m_raw,
    const float* __restrict__ attn_out_w, const float* __restrict__ Wfs, const float* __restrict__ Wfsh,
    const float* __restrict__ fsm, const float* __restrict__ fshm)
{
    __shared__ float mbuf[4][64], mobuf[4][64];
    int wave = threadIdx.x >> 6, lane = threadIdx.x & 63;
    int task = blockIdx.x * 4 + wave;                 // b*N + n
    int b = task / NN;
    int slot = col2slot[task];
    float* hp = h + task * DS;
    float hv = hp[lane];
    if (slot >= 0) mbuf[wave][lane] = m_raw[(b * KK + slot) * DV + lane];
    __syncthreads();
    float mo = 0.f;
    if (slot >= 0) {
        const float* wo = attn_out_w + lane * DV;
#pragma unroll
        for (int e = 0; e < DV; e++) mo += mbuf[wave][e] * wo[e];
        mobuf[wave][lane] = mo;
    }
    __syncthreads();
    float nh;
    if (slot >= 0) {
        const float* ws = Wfs + lane * DV;
        const float* wsh = Wfsh + lane * DV;
        float sc = 0.f, sh = 0.f;
#pragma unroll
        for (int e = 0; e < DV; e++) { float z = mobuf[wave][e]; sc += z * ws[e]; sh += z * wsh[e]; }
        nh = hv * (1.0f + tanhf(sc)) + sh;
    } else {
        nh = hv * (1.0f + fsm[b * DS + lane]) + fshm[b * DS + lane];
    }
    hp[lane] = nh;
}

// ---------------------------------------------------------------- K7: pooling + output projection
__global__ __launch_bounds__(1024) void k_pool(
    const float* __restrict__ h, const float* __restrict__ query, const float* __restrict__ onw,
    const float* __restrict__ W_out, float* __restrict__ out, int t)
{
    int b = blockIdx.x, tid = threadIdx.x;
    __shared__ float pl[NN];
    __shared__ float red[1024];
    __shared__ float part[16][64];
    __shared__ float pooled[64];
    __shared__ float qv[64];
    if (tid < 64) qv[tid] = query[tid];
    __syncthreads();
    const float* hb = h + b * NN * DS;
    for (int n = tid; n < NN; n += 1024) {
        const float* hp = hb + n * DS;
        float acc = 0.f;
#pragma unroll
        for (int d = 0; d < DS; d++) acc += qv[d] * hp[d];
        pl[n] = acc * 0.125f;                         // /sqrt(64)
    }
    __syncthreads();
    red[tid] = fmaxf(pl[tid], pl[tid + 1024]);
    __syncthreads();
    for (int s = 512; s > 0; s >>= 1) { if (tid < s) red[tid] = fmaxf(red[tid], red[tid + s]); __syncthreads(); }
    float mx = red[0];
    __syncthreads();
    float e0 = expf(pl[tid] - mx), e1 = expf(pl[tid + 1024] - mx);
    pl[tid] = e0; pl[tid + 1024] = e1;
    red[tid] = e0 + e1;
    __syncthreads();
    for (int s = 512; s > 0; s >>= 1) { if (tid < s) red[tid] += red[tid + s]; __syncthreads(); }
    float inv = 1.0f / red[0];
    __syncthreads();
    int d = tid & 63, seg = tid >> 6;
    float acc = 0.f;
    for (int n = seg * 128; n < seg * 128 + 128; n++) acc += pl[n] * hb[n * DS + d];
    part[seg][d] = acc;
    __syncthreads();
    if (tid < 64) {
        float s = 0.f;
#pragma unroll
        for (int g = 0; g < 16; g++) s += part[g][tid];
        float v = s * inv;
        float ssv = wave_sum(v * v);
        float rs = rsqrtf(ssv * (1.0f / DS) + 1e-6f);
        pooled[tid] = onw[tid] * v * rs;
    }
    __syncthreads();
    if (tid < DI) {
        const float* wr = W_out + tid * DS;
        float acc2 = 0.f;
#pragma unroll
        for (int dd = 0; dd < DS; dd++) acc2 += pooled[dd] * wr[dd];
        out[(b * TT + t) * DI + tid] = acc2;
    }
}

// ----------------------------------------------------------------
extern "C" void kernel_launch(void* const* d_in, const int* in_sizes, int n_in,
                              void* d_out, int out_size, void* d_ws, size_t ws_size,
                              hipStream_t stream)
{
    const float* x          = (const float*)d_in[0];
    const float* W_in       = (const float*)d_in[1];
    const float* core_norm_w= (const float*)d_in[2];
    const float* core_Wg    = (const float*)d_in[3];
    const float* core_Wout  = (const float*)d_in[4];
    const float* W_gate     = (const float*)d_in[5];
    const float* W_vote     = (const float*)d_in[6];
    const float* attn_in_w  = (const float*)d_in[7];
    const float* attn_out_w = (const float*)d_in[8];
    const float* Wfs        = (const float*)d_in[9];
    const float* Wfsh       = (const float*)d_in[10];
    const float* query      = (const float*)d_in[11];
    const float* onw        = (const float*)d_in[12];
    const float* W_out      = (const float*)d_in[13];
    float* out = (float*)d_out;

    float* ws = (float*)d_ws;
    size_t off = 0;
    float* h       = ws + off; off += (size_t)BB * NN * DS;   // 262144
    float* gate    = ws + off; off += BB * NN;                // 4096
    float* xproj   = ws + off; off += BB * DS;                // 128
    int*   col2slot= (int*)(ws + off); off += BB * NN;        // 4096
    int*   act_idx = (int*)(ws + off); off += BB * KK;        // 1024
    float* qh      = ws + off; off += BB * HH * KK * HD;      // 65536
    float* kh      = ws + off; off += BB * HH * KK * HD;
    float* vh      = ws + off; off += BB * HH * KK * HD;
    float* m_raw   = ws + off; off += BB * KK * DV;           // 65536
    float* fsm     = ws + off; off += BB * DS;
    float* fshm    = ws + off; off += BB * DS;

    hipMemsetAsync(h, 0, (size_t)BB * NN * DS * sizeof(float), stream);

    for (int t = 0; t < TT; t++) {
        k_gate_xproj<<<17, 256, 0, stream>>>(h, W_gate, x, W_in, gate, xproj, t);
        k_topk<<<BB, 1024, 0, stream>>>(gate, col2slot, act_idx);
        k_core<<<BB * KK / 4, 256, 0, stream>>>(h, xproj, act_idx, core_norm_w, core_Wg, core_Wout);
        k_votes<<<BB * KK / 4, 256, 0, stream>>>(h, act_idx, W_vote, attn_in_w, qh, kh, vh);
        k_attn<<<BB * HH * KK / 4, 256, 0, stream>>>(qh, kh, vh, m_raw);
        k_meanfilm<<<1, 512, 0, stream>>>(vh, attn_out_w, Wfs, Wfsh, fsm, fshm);
        k_film<<<BB * NN / 4, 256, 0, stream>>>(h, col2slot, m_raw, attn_out_w, Wfs, Wfsh, fsm, fshm);
        k_pool<<<BB, 1024, 0, stream>>>(h, query, onw, W_out, out, t);
    }
}